// Round 9
// baseline (618.917 us; speedup 1.0000x reference)
//
#include <hip/hip_runtime.h>
#include <hip/hip_bf16.h>
#include <cstdint>

#define D_MODEL 384
#define NHEAD 6
#define DHEAD 64
#define NPTS 2048
#define BATCH 8

typedef __attribute__((ext_vector_type(8))) short short8;
typedef __attribute__((ext_vector_type(4))) float floatx4;

__device__ __forceinline__ float bf2f(unsigned short u) {
    return __uint_as_float(((unsigned int)u) << 16);
}

// round-to-nearest-even f32 -> bf16 (finite inputs only)
__device__ __forceinline__ unsigned short f2bf(float f) {
    unsigned int u = __float_as_uint(f);
    unsigned int r = (u + 0x7FFFu + ((u >> 16) & 1u)) >> 16;
    return (unsigned short)r;
}

__device__ __forceinline__ float gelu_tanh(float x) {
    float x3 = x * x * x;
    return 0.5f * x * (1.0f + tanhf(0.7978845608028654f * (x + 0.044715f * x3)));
}

// async 16B global -> LDS (wave-uniform LDS base + lane*16)
__device__ __forceinline__ void gload_lds16(const unsigned short* g, unsigned short* l) {
    __builtin_amdgcn_global_load_lds(
        (const __attribute__((address_space(1))) unsigned int*)g,
        (__attribute__((address_space(3))) unsigned int*)l, 16, 0, 0);
}

// Weight prep: fp32 [K,N] -> bf16 [N,K] (transposed), all 8 weights in one dispatch.
__global__ __launch_bounds__(256) void k_wprep(
    const float* __restrict__ wqkv, const float* __restrict__ wao,
    const float* __restrict__ wq, const float* __restrict__ wk,
    const float* __restrict__ wv, const float* __restrict__ wm,
    const float* __restrict__ w1, const float* __restrict__ w2,
    unsigned short* __restrict__ qkvT, unsigned short* __restrict__ aoT,
    unsigned short* __restrict__ gaT, unsigned short* __restrict__ mT,
    unsigned short* __restrict__ f1T, unsigned short* __restrict__ f2T) {
    __shared__ float tile[32][33];
    int id = blockIdx.x;
    const float* src;
    unsigned short* dst;
    int K, N;
    if (id < 432)       {            src = wqkv; dst = qkvT;            K = 384; N = 1152; }
    else if (id < 576)  { id -= 432; src = wao;  dst = aoT;             K = 384; N = 384; }
    else if (id < 720)  { id -= 576; src = wq;   dst = gaT;             K = 384; N = 384; }
    else if (id < 864)  { id -= 720; src = wk;   dst = gaT + 384 * 384; K = 384; N = 384; }
    else if (id < 1008) { id -= 864; src = wv;   dst = gaT + 768 * 384; K = 384; N = 384; }
    else if (id < 1296) { id -= 1008; src = wm;  dst = mT;              K = 768; N = 384; }
    else if (id < 1584) { id -= 1296; src = w1;  dst = f1T;             K = 384; N = 768; }
    else                { id -= 1584; src = w2;  dst = f2T;             K = 768; N = 384; }
    int ntiles = N >> 5;
    int nt = id % ntiles, kt = id / ntiles;
    int tx = threadIdx.x, ty = threadIdx.y;
#pragma unroll
    for (int i = 0; i < 32; i += 8)
        tile[ty + i][tx] = src[(size_t)(kt * 32 + ty + i) * N + nt * 32 + tx];
    __syncthreads();
#pragma unroll
    for (int i = 0; i < 32; i += 8)
        dst[(size_t)(nt * 32 + ty + i) * K + kt * 32 + tx] = f2bf(tile[tx][ty + i]);
}

// features fp32 [B, D, N] -> F bf16 [B, N, D]
__global__ __launch_bounds__(256) void k_transpose_in(const float* __restrict__ feat,
                                                      unsigned short* __restrict__ f) {
    __shared__ float tile[32][33];
    int b = blockIdx.z;
    int n0 = blockIdx.x * 32, d0 = blockIdx.y * 32;
    int tx = threadIdx.x, ty = threadIdx.y;
#pragma unroll
    for (int i = 0; i < 32; i += 8)
        tile[ty + i][tx] = feat[((size_t)b * D_MODEL + d0 + ty + i) * NPTS + n0 + tx];
    __syncthreads();
#pragma unroll
    for (int i = 0; i < 32; i += 8)
        f[((size_t)b * NPTS + n0 + ty + i) * D_MODEL + d0 + tx] = f2bf(tile[tx][ty + i]);
}

// FFIN bf16 [B, N, D] -> out fp32 [B, D, N]
__global__ __launch_bounds__(256) void k_transpose_out(const unsigned short* __restrict__ f,
                                                       float* __restrict__ out) {
    __shared__ float tile[32][33];
    int b = blockIdx.z;
    int d0 = blockIdx.x * 32, n0 = blockIdx.y * 32;
    int tx = threadIdx.x, ty = threadIdx.y;
#pragma unroll
    for (int i = 0; i < 32; i += 8)
        tile[ty + i][tx] = bf2f(f[((size_t)b * NPTS + n0 + ty + i) * D_MODEL + d0 + tx]);
    __syncthreads();
#pragma unroll
    for (int i = 0; i < 32; i += 8)
        out[((size_t)b * D_MODEL + d0 + ty + i) * NPTS + n0 + tx] = tile[tx][ty + i];
}

// V slice of QKV [M,1152] (cols 768..1152) -> VT [B,H,64,NPTS]
__global__ __launch_bounds__(256) void k_vt(const unsigned short* __restrict__ qkv,
                                            unsigned short* __restrict__ vt) {
    __shared__ unsigned short tile[32][33];
    int b = blockIdx.z;
    int h = blockIdx.y >> 1, d0 = (blockIdx.y & 1) * 32;
    int n0 = blockIdx.x * 32;
    int tx = threadIdx.x, ty = threadIdx.y;
#pragma unroll
    for (int i = 0; i < 32; i += 8)
        tile[ty + i][tx] =
            qkv[((size_t)b * NPTS + n0 + ty + i) * 1152 + 768 + h * 64 + d0 + tx];
    __syncthreads();
#pragma unroll
    for (int i = 0; i < 32; i += 8)
        vt[(((size_t)(b * NHEAD + h) * 64) + d0 + ty + i) * NPTS + n0 + tx] = tile[tx][ty + i];
}

// LayerNorm over D=384 (bf16 in/out, fp32 g/b), one block (128 thr) per row
__global__ __launch_bounds__(128) void k_layernorm(const unsigned short* __restrict__ x,
                                                   const float* __restrict__ g,
                                                   const float* __restrict__ bt,
                                                   unsigned short* __restrict__ y) {
    int row = blockIdx.x, t = threadIdx.x;
    const unsigned short* xr = x + (size_t)row * D_MODEL;
    float v0 = bf2f(xr[t]), v1 = bf2f(xr[t + 128]), v2 = bf2f(xr[t + 256]);
    float s = v0 + v1 + v2;
    float s2 = v0 * v0 + v1 * v1 + v2 * v2;
#pragma unroll
    for (int off = 32; off > 0; off >>= 1) {
        s += __shfl_xor(s, off, 64);
        s2 += __shfl_xor(s2, off, 64);
    }
    __shared__ float ps[2], ps2[2];
    if ((t & 63) == 0) { ps[t >> 6] = s; ps2[t >> 6] = s2; }
    __syncthreads();
    s = ps[0] + ps[1];
    s2 = ps2[0] + ps2[1];
    float mean = s * (1.0f / 384.0f);
    float var = s2 * (1.0f / 384.0f) - mean * mean;
    var = fmaxf(var, 0.0f);
    float inv = 1.0f / sqrtf(var + 1e-5f);
    unsigned short* yr = y + (size_t)row * D_MODEL;
    yr[t]       = f2bf((v0 - mean) * inv * g[t]       + bt[t]);
    yr[t + 128] = f2bf((v1 - mean) * inv * g[t + 128] + bt[t + 128]);
    yr[t + 256] = f2bf((v2 - mean) * inv * g[t + 256] + bt[t + 256]);
}

// KNN: LDS-resident candidates, 8 threads/query, interleaved partitions.
__global__ __launch_bounds__(256) void k_knn(const float* __restrict__ coords,
                                             int* __restrict__ idx) {
    __shared__ float4 cpts[NPTS];
    __shared__ unsigned long long mbuf[32][8][8];
    int b = blockIdx.x >> 6;
    int n0 = (blockIdx.x & 63) * 32;
    const float* cb = coords + (size_t)b * 3 * NPTS;
    int tid = threadIdx.x;
#pragma unroll
    for (int i = 0; i < 8; i++) {
        int m = tid + i * 256;
        float x = cb[m], y = cb[NPTS + m], z = cb[2 * NPTS + m];
        float sq = __fadd_rn(__fadd_rn(__fmul_rn(x, x), __fmul_rn(y, y)), __fmul_rn(z, z));
        cpts[m] = make_float4(x, y, z, sq);
    }
    __syncthreads();
    int q = tid >> 3;
    int part = tid & 7;
    int n = n0 + q;
    float4 qp = cpts[n];
    float qx = qp.x, qy = qp.y, qz = qp.z, sqn = qp.w;
    unsigned long long heap[8];
#pragma unroll
    for (int k = 0; k < 8; k++) heap[k] = 0xFFFFFFFFFFFFFFFFull;
    for (int j = 0; j < 256; j++) {
        int m = j * 8 + part;
        float4 cp = cpts[m];
        float dot = __fadd_rn(__fadd_rn(__fmul_rn(qx, cp.x), __fmul_rn(qy, cp.y)),
                              __fmul_rn(qz, cp.z));
        float d2 = __fsub_rn(__fadd_rn(sqn, cp.w), __fmul_rn(2.0f, dot));
        unsigned int u = __float_as_uint(d2);
        u = (u & 0x80000000u) ? ~u : (u | 0x80000000u);
        unsigned long long key = ((unsigned long long)u << 32) | (unsigned int)m;
        if (key < heap[7]) {
            heap[7] = key;
#pragma unroll
            for (int t2 = 7; t2 > 0; t2--) {
                if (heap[t2] < heap[t2 - 1]) {
                    unsigned long long tmp = heap[t2];
                    heap[t2] = heap[t2 - 1];
                    heap[t2 - 1] = tmp;
                }
            }
        }
    }
#pragma unroll
    for (int k = 0; k < 8; k++) mbuf[q][part][k] = heap[k];
    __syncthreads();
    if (part == 0) {
        int p[8] = {0, 0, 0, 0, 0, 0, 0, 0};
        int* outr = idx + ((size_t)b * NPTS + n) * 8;
#pragma unroll
        for (int k = 0; k < 8; k++) {
            unsigned long long best = mbuf[q][0][p[0]];
            int bi = 0;
#pragma unroll
            for (int c = 1; c < 8; c++) {
                unsigned long long v = mbuf[q][c][p[c]];
                if (v < best) { best = v; bi = c; }
            }
            p[bi]++;
            outr[k] = (int)(best & 0xFFFFFFFFu);
        }
    }
}

// MFMA GEMM v4: 128x128 tile, BK=32. A staged via async global_load_lds (16B);
// B (weights, L2-hot) read directly from global as MFMA frags — no W LDS at all.
// A bf16 [M,K] (lda), WT bf16 [N,K], bias fp32, res/C bf16 (ldc).
__global__ __launch_bounds__(256) void k_gemm(const unsigned short* __restrict__ A, int lda,
                                              const unsigned short* __restrict__ WT,
                                              const float* __restrict__ bias,
                                              const unsigned short* __restrict__ res,
                                              unsigned short* __restrict__ C, int ldc,
                                              int K, int act) {
    __shared__ unsigned short Alds[128 * 32];  // 8 KB, [m][k] contiguous
    int tid = threadIdx.x;
    int wv = tid >> 6, lane = tid & 63;
    int l15 = lane & 15, quad = lane >> 4;
    int row0 = blockIdx.y * 128, col0 = blockIdx.x * 128;
    int wm = wv >> 1, wn = wv & 1;
    floatx4 acc[4][4];
#pragma unroll
    for (int i = 0; i < 4; i++)
#pragma unroll
        for (int j = 0; j < 4; j++) acc[i][j] = (floatx4){0.f, 0.f, 0.f, 0.f};
    int wbase = tid & 192;  // wv*64
    for (int k0 = 0; k0 < K; k0 += 32) {
#pragma unroll
        for (int i = 0; i < 2; i++) {
            int idx = i * 256 + tid;
            const unsigned short* gp = A + (size_t)(row0 + (idx >> 2)) * lda + k0 + (idx & 3) * 8;
            gload_lds16(gp, &Alds[(size_t)(i * 256 + wbase) * 8]);
        }
        short8 bf[4];
#pragma unroll
        for (int j = 0; j < 4; j++)
            bf[j] = *(const short8*)(WT + (size_t)(col0 + wn * 64 + j * 16 + l15) * K + k0 +
                                     quad * 8);
        __syncthreads();  // drains global_load_lds (vmcnt) + waits B frags
        short8 af[4];
#pragma unroll
        for (int i = 0; i < 4; i++)
            af[i] = *(const short8*)&Alds[(wm * 64 + i * 16 + l15) * 32 + quad * 8];
#pragma unroll
        for (int i = 0; i < 4; i++)
#pragma unroll
            for (int j = 0; j < 4; j++)
                acc[i][j] = __builtin_amdgcn_mfma_f32_16x16x32_bf16(af[i], bf[j], acc[i][j], 0, 0, 0);
        __syncthreads();
    }
#pragma unroll
    for (int i = 0; i < 4; i++)
#pragma unroll
        for (int j = 0; j < 4; j++) {
            int cbase = col0 + wn * 64 + j * 16 + l15;
            float bv = bias ? bias[cbase] : 0.0f;
#pragma unroll
            for (int reg = 0; reg < 4; reg++) {
                int r = row0 + wm * 64 + i * 16 + quad * 4 + reg;
                float v = acc[i][j][reg] + bv;
                if (act == 1) v = gelu_tanh(v);
                if (res) v += bf2f(res[(size_t)r * ldc + cbase]);
                C[(size_t)r * ldc + cbase] = f2bf(v);
            }
        }
}

// MFMA flash attention v4: no-max softmax (p = exp2(s), Q pre-scaled by
// 0.125*log2e at load), V pre-transposed in global (VT [B,H,64,NPTS]) so V
// staging is pure vector copies. Per-lane denominator, one reduction at end.
__global__ __launch_bounds__(256) void k_attn(const unsigned short* __restrict__ qkv,
                                              const unsigned short* __restrict__ vt,
                                              unsigned short* __restrict__ attn) {
    __shared__ unsigned short Klds[64 * 72];       // [key][dim]
    __shared__ unsigned short VT[64 * 72];         // [dim][key]
    __shared__ unsigned short Plds[4][2][16 * 40]; // per-wave [query][key] pitch 40
    __shared__ float lSm[4][32];
    int b = blockIdx.z, h = blockIdx.y;
    int tid = threadIdx.x;
    int wv = tid >> 6, lane = tid & 63;
    int l15 = lane & 15, quad = lane >> 4;
    int qbase = blockIdx.x * 128 + wv * 32;
    const unsigned short* qkvb = qkv + (size_t)b * NPTS * 1152;
    const unsigned short* vtb = vt + (size_t)(b * NHEAD + h) * 64 * NPTS;
    const float SC = 0.18033688011112042f;  // 0.125 * log2(e)
    short8 qf[2][2];
#pragma unroll
    for (int qt = 0; qt < 2; qt++) {
        const unsigned short* qptr =
            qkvb + (size_t)(qbase + qt * 16 + l15) * 1152 + h * 64 + quad * 8;
        qf[qt][0] = *(const short8*)qptr;
        qf[qt][1] = *(const short8*)(qptr + 32);
#pragma unroll
        for (int g = 0; g < 2; g++) {  // fold softmax scale into Q once
            short8 v = qf[qt][g];
#pragma unroll
            for (int e = 0; e < 8; e++)
                v[e] = (short)f2bf(bf2f((unsigned short)v[e]) * SC);
            qf[qt][g] = v;
        }
    }
    floatx4 o[2][4];
#pragma unroll
    for (int qt = 0; qt < 2; qt++)
#pragma unroll
        for (int ct = 0; ct < 4; ct++) o[qt][ct] = (floatx4){0.f, 0.f, 0.f, 0.f};
    float lacc[2][4];
#pragma unroll
    for (int qt = 0; qt < 2; qt++)
#pragma unroll
        for (int r = 0; r < 4; r++) lacc[qt][r] = 0.0f;
    for (int k0 = 0; k0 < NPTS; k0 += 64) {
#pragma unroll
        for (int i = 0; i < 2; i++) {
            int s = tid + i * 256;
            int key = s >> 3, dg = s & 7;
            *(uint4*)&Klds[key * 72 + dg * 8] =
                *(const uint4*)(qkvb + (size_t)(k0 + key) * 1152 + 384 + h * 64 + dg * 8);
            int dim = s >> 3, kc = s & 7;
            *(uint4*)&VT[dim * 72 + kc * 8] =
                *(const uint4*)(vtb + (size_t)dim * NPTS + k0 + kc * 8);
        }
        __syncthreads();
#pragma unroll
        for (int qt = 0; qt < 2; qt++) {
            floatx4 s4[4];
#pragma unroll
            for (int ct = 0; ct < 4; ct++) {
                short8 kf0 = *(const short8*)&Klds[(ct * 16 + l15) * 72 + quad * 8];
                short8 kf1 = *(const short8*)&Klds[(ct * 16 + l15) * 72 + 32 + quad * 8];
                floatx4 z = (floatx4){0.f, 0.f, 0.f, 0.f};
                z = __builtin_amdgcn_mfma_f32_16x16x32_bf16(qf[qt][0], kf0, z, 0, 0, 0);
                z = __builtin_amdgcn_mfma_f32_16x16x32_bf16(qf[qt][1], kf1, z, 0, 0, 0);
                s4[ct] = z;
            }
            unsigned short* pw = &Plds[wv][qt][0];
#pragma unroll
            for (int ct = 0; ct < 4; ct++)
#pragma unroll
                for (int r = 0; r < 4; r++) {
                    float p = exp2f(s4[ct][r]);
                    lacc[qt][r] += p;
                    pw[(quad * 4 + r) * 40 + ct * 16 + l15] = f2bf(p);
                }
        }
        short8 pf[2][2];
#pragma unroll
        for (int qt = 0; qt < 2; qt++)
#pragma unroll
            for (int g = 0; g < 2; g++)
                pf[qt][g] = *(const short8*)&Plds[wv][qt][l15 * 40 + g * 32 + quad * 8];
#pragma unroll
        for (int ct = 0; ct < 4; ct++) {
            short8 vt0 = *(const short8*)&VT[(ct * 16 + l15) * 72 + quad * 8];
            short8 vt1 = *(const short8*)&VT[(ct * 16 + l15) * 72 + 32 + quad * 8];
#pragma unroll
            for (int qt = 0; qt < 2; qt++) {
                o[qt][ct] = __builtin_amdgcn_mfma_f32_16x16x32_bf16(vt0, pf[qt][0], o[qt][ct], 0, 0, 0);
                o[qt][ct] = __builtin_amdgcn_mfma_f32_16x16x32_bf16(vt1, pf[qt][1], o[qt][ct], 0, 0, 0);
            }
        }
        __syncthreads();
    }
#pragma unroll
    for (int off = 1; off < 16; off <<= 1)
#pragma unroll
        for (int qt = 0; qt < 2; qt++)
#pragma unroll
            for (int r = 0; r < 4; r++) lacc[qt][r] += __shfl_xor(lacc[qt][r], off, 64);
    if (l15 == 0) {
#pragma unroll
        for (int qt = 0; qt < 2; qt++)
#pragma unroll
            for (int r = 0; r < 4; r++) lSm[wv][qt * 16 + quad * 4 + r] = lacc[qt][r];
    }
#pragma unroll
    for (int qt = 0; qt < 2; qt++) {
        float linv = 1.0f / lSm[wv][qt * 16 + l15];
#pragma unroll
        for (int ct = 0; ct < 4; ct++) {
            ushort4 u;
            u.x = f2bf(o[qt][ct][0] * linv);
            u.y = f2bf(o[qt][ct][1] * linv);
            u.z = f2bf(o[qt][ct][2] * linv);
            u.w = f2bf(o[qt][ct][3] * linv);
            *(ushort4*)(attn + ((size_t)b * NPTS + qbase + qt * 16 + l15) * 384 + h * 64 +
                        ct * 16 + quad * 4) = u;
        }
    }
}

// Graph attention: gq/nk/nv are column-slices of GAP [M,1152]. One wave per point.
// Writes geom into CAT[:, 384:768] (row stride 768).
__global__ __launch_bounds__(64) void k_geom(const unsigned short* __restrict__ gap,
                                             const int* __restrict__ idx,
                                             unsigned short* __restrict__ cat) {
    int r = blockIdx.x;
    int b = r >> 11;
    int t = threadIdx.x;
    int nb[8];
#pragma unroll
    for (int k = 0; k < 8; k++) nb[k] = idx[(size_t)r * 8 + k];
    const unsigned short* gqr = gap + (size_t)r * 1152;
    float qv[6];
#pragma unroll
    for (int j = 0; j < 6; j++) qv[j] = bf2f(gqr[t + 64 * j]);
    float s[8];
#pragma unroll
    for (int k = 0; k < 8; k++) {
        const unsigned short* nkr = gap + ((size_t)b * NPTS + nb[k]) * 1152 + 384;
        float acc = 0.0f;
#pragma unroll
        for (int j = 0; j < 6; j++) acc += qv[j] * bf2f(nkr[t + 64 * j]);
#pragma unroll
        for (int mm = 32; mm > 0; mm >>= 1) acc += __shfl_xor(acc, mm, 64);
        s[k] = acc * 0.05103103630798287f;  // 1/sqrt(384)
    }
    float mx = s[0];
#pragma unroll
    for (int k = 1; k < 8; k++) mx = fmaxf(mx, s[k]);
    float w[8];
    float sum = 0.0f;
#pragma unroll
    for (int k = 0; k < 8; k++) { w[k] = __expf(s[k] - mx); sum += w[k]; }
    float inv = 1.0f / sum;
    unsigned short* outr = cat + (size_t)r * 768 + 384;
#pragma unroll
    for (int j = 0; j < 6; j++) {
        int d = t + 64 * j;
        float acc = 0.0f;
#pragma unroll
        for (int k = 0; k < 8; k++)
            acc += w[k] * bf2f(gap[((size_t)b * NPTS + nb[k]) * 1152 + 768 + d]);
        outr[d] = f2bf(acc * inv);
    }
}

extern "C" void kernel_launch(void* const* d_in, const int* in_sizes, int n_in,
                              void* d_out, int out_size, void* d_ws, size_t ws_size,
                              hipStream_t stream) {
    (void)in_sizes; (void)n_in; (void)out_size; (void)ws_size;
    const float* coords     = (const float*)d_in[0];
    const float* features   = (const float*)d_in[1];
    const float* ln1_g      = (const float*)d_in[2];
    const float* ln1_b      = (const float*)d_in[3];
    const float* w_qkv      = (const float*)d_in[4];
    const float* w_attn_out = (const float*)d_in[5];
    const float* b_attn_out = (const float*)d_in[6];
    const float* ga_wq      = (const float*)d_in[7];
    const float* ga_wk      = (const float*)d_in[8];
    const float* ga_wv      = (const float*)d_in[9];
    const float* merge_w    = (const float*)d_in[10];
    const float* merge_b    = (const float*)d_in[11];
    const float* ln2_g      = (const float*)d_in[12];
    const float* ln2_b      = (const float*)d_in[13];
    const float* ff_w1      = (const float*)d_in[14];
    const float* ff_b1      = (const float*)d_in[15];
    const float* ff_w2      = (const float*)d_in[16];
    const float* ff_b2      = (const float*)d_in[17];

    // Workspace (bf16 units of SZ = 6,291,456 elems = 12 MiB). Overlay schedule:
    //   u0 F | u1 NF->HB | u2-4 QKV -> (CAT=u2-3, GAP=u4-6 after attn/AO) |
    //   u5 ATTN | u6 VT (dead before GAP gemm) | F2=u4 after geom | T1=u5-6 |
    //   FFIN=u2 | IDX + transposed weights after u7 (~4.3 MB). Peak ~100 MiB.
    unsigned short* W0 = (unsigned short*)d_ws;
    const size_t SZ = (size_t)BATCH * NPTS * D_MODEL;  // 6291456
    unsigned short* F    = W0 + 0 * SZ;
    unsigned short* NF   = W0 + 1 * SZ;
    unsigned short* QKV  = W0 + 2 * SZ;   // 3 units
    unsigned short* ATTN = W0 + 5 * SZ;
    unsigned short* VT   = W0 + 6 * SZ;   // [B,H,64,NPTS] = 1 unit
    unsigned short* CAT  = W0 + 2 * SZ;   // 2 units [M,768]
    unsigned short* GAP  = W0 + 4 * SZ;   // 3 units [M,1152]
    unsigned short* F2   = W0 + 4 * SZ;   // after GAP dead
    unsigned short* HB   = W0 + 1 * SZ;
    unsigned short* T1   = W0 + 5 * SZ;   // 2 units [M,768]
    unsigned short* FFIN = W0 + 2 * SZ;
    int*            IDX  = (int*)(W0 + 7 * SZ);
    unsigned short* WTS  = W0 + 7 * SZ + 262144;  // after IDX (512 KB)
    unsigned short* qkvT = WTS;                     // [1152,384]
    unsigned short* aoT  = qkvT + 442368;           // [384,384]
    unsigned short* gaT  = aoT + 147456;            // [1152,384]
    unsigned short* mT   = gaT + 442368;            // [384,768]
    unsigned short* f1T  = mT + 294912;             // [768,384]
    unsigned short* f2T  = f1T + 294912;            // [384,768]

    const int M = BATCH * NPTS;  // 16384

    k_wprep<<<1872, dim3(32, 8), 0, stream>>>(w_qkv, w_attn_out, ga_wq, ga_wk, ga_wv,
                                              merge_w, ff_w1, ff_w2,
                                              qkvT, aoT, gaT, mT, f1T, f2T);
    k_transpose_in<<<dim3(NPTS / 32, D_MODEL / 32, BATCH), dim3(32, 8), 0, stream>>>(features, F);
    k_layernorm<<<M, 128, 0, stream>>>(F, ln1_g, ln1_b, NF);
    k_knn<<<BATCH * (NPTS / 32), 256, 0, stream>>>(coords, IDX);
    // QKV = NF @ w_qkv
    k_gemm<<<dim3(9, M / 128), 256, 0, stream>>>(NF, 384, qkvT, nullptr, nullptr,
                                                 QKV, 1152, 384, 0);
    k_vt<<<dim3(NPTS / 32, 2 * NHEAD, BATCH), dim3(32, 8), 0, stream>>>(QKV, VT);
    k_attn<<<dim3(NPTS / 128, NHEAD, BATCH), 256, 0, stream>>>(QKV, VT, ATTN);
    // CAT[:, :384] = ATTN @ w_attn_out + b_attn_out
    k_gemm<<<dim3(3, M / 128), 256, 0, stream>>>(ATTN, 384, aoT, b_attn_out, nullptr,
                                                 CAT, 768, 384, 0);
    // GAP = NF @ [ga_wq | ga_wk | ga_wv]
    k_gemm<<<dim3(9, M / 128), 256, 0, stream>>>(NF, 384, gaT, nullptr, nullptr,
                                                 GAP, 1152, 384, 0);
    k_geom<<<M, 64, 0, stream>>>(GAP, IDX, CAT);
    // F2 = CAT @ merge_w + merge_b + F
    k_gemm<<<dim3(3, M / 128), 256, 0, stream>>>(CAT, 768, mT, merge_b, F,
                                                 F2, 384, 768, 0);
    k_layernorm<<<M, 128, 0, stream>>>(F2, ln2_g, ln2_b, HB);
    // T1 = gelu(HB @ ff_w1 + ff_b1)
    k_gemm<<<dim3(6, M / 128), 256, 0, stream>>>(HB, 384, f1T, ff_b1, nullptr,
                                                 T1, 768, 384, 1);
    // FFIN = F2 + T1 @ ff_w2 + ff_b2
    k_gemm<<<dim3(3, M / 128), 256, 0, stream>>>(T1, 768, f2T, ff_b2, F2,
                                                 FFIN, 384, 768, 0);
    k_transpose_out<<<dim3(D_MODEL / 32, NPTS / 32, BATCH), dim3(32, 8), 0, stream>>>(
        FFIN, (float*)d_out);
}

// Round 10
// 550.355 us; speedup vs baseline: 1.1246x; 1.1246x over previous
//
#include <hip/hip_runtime.h>
#include <hip/hip_bf16.h>
#include <cstdint>

#define D_MODEL 384
#define NHEAD 6
#define DHEAD 64
#define NPTS 2048
#define BATCH 8

typedef __attribute__((ext_vector_type(8))) short short8;
typedef __attribute__((ext_vector_type(4))) float floatx4;

__device__ __forceinline__ float bf2f(unsigned short u) {
    return __uint_as_float(((unsigned int)u) << 16);
}

// round-to-nearest-even f32 -> bf16 (finite inputs only)
__device__ __forceinline__ unsigned short f2bf(float f) {
    unsigned int u = __float_as_uint(f);
    unsigned int r = (u + 0x7FFFu + ((u >> 16) & 1u)) >> 16;
    return (unsigned short)r;
}

__device__ __forceinline__ float gelu_tanh(float x) {
    float x3 = x * x * x;
    return 0.5f * x * (1.0f + tanhf(0.7978845608028654f * (x + 0.044715f * x3)));
}

// async 16B global -> LDS (wave-uniform LDS base + lane*16)
__device__ __forceinline__ void gload_lds16(const unsigned short* g, unsigned short* l) {
    __builtin_amdgcn_global_load_lds(
        (const __attribute__((address_space(1))) unsigned int*)g,
        (__attribute__((address_space(3))) unsigned int*)l, 16, 0, 0);
}

// Weight prep: fp32 [K,N] -> bf16 [N,K] (transposed), all 8 weights in one dispatch.
__global__ __launch_bounds__(256) void k_wprep(
    const float* __restrict__ wqkv, const float* __restrict__ wao,
    const float* __restrict__ wq, const float* __restrict__ wk,
    const float* __restrict__ wv, const float* __restrict__ wm,
    const float* __restrict__ w1, const float* __restrict__ w2,
    unsigned short* __restrict__ qkvT, unsigned short* __restrict__ aoT,
    unsigned short* __restrict__ gaT, unsigned short* __restrict__ mT,
    unsigned short* __restrict__ f1T, unsigned short* __restrict__ f2T) {
    __shared__ float tile[32][33];
    int id = blockIdx.x;
    const float* src;
    unsigned short* dst;
    int K, N;
    if (id < 432)       {            src = wqkv; dst = qkvT;            K = 384; N = 1152; }
    else if (id < 576)  { id -= 432; src = wao;  dst = aoT;             K = 384; N = 384; }
    else if (id < 720)  { id -= 576; src = wq;   dst = gaT;             K = 384; N = 384; }
    else if (id < 864)  { id -= 720; src = wk;   dst = gaT + 384 * 384; K = 384; N = 384; }
    else if (id < 1008) { id -= 864; src = wv;   dst = gaT + 768 * 384; K = 384; N = 384; }
    else if (id < 1296) { id -= 1008; src = wm;  dst = mT;              K = 768; N = 384; }
    else if (id < 1584) { id -= 1296; src = w1;  dst = f1T;             K = 384; N = 768; }
    else                { id -= 1584; src = w2;  dst = f2T;             K = 768; N = 384; }
    int ntiles = N >> 5;
    int nt = id % ntiles, kt = id / ntiles;
    int tx = threadIdx.x, ty = threadIdx.y;
#pragma unroll
    for (int i = 0; i < 32; i += 8)
        tile[ty + i][tx] = src[(size_t)(kt * 32 + ty + i) * N + nt * 32 + tx];
    __syncthreads();
#pragma unroll
    for (int i = 0; i < 32; i += 8)
        dst[(size_t)(nt * 32 + ty + i) * K + kt * 32 + tx] = f2bf(tile[tx][ty + i]);
}

// features fp32 [B, D, N] -> F bf16 [B, N, D]
__global__ __launch_bounds__(256) void k_transpose_in(const float* __restrict__ feat,
                                                      unsigned short* __restrict__ f) {
    __shared__ float tile[32][33];
    int b = blockIdx.z;
    int n0 = blockIdx.x * 32, d0 = blockIdx.y * 32;
    int tx = threadIdx.x, ty = threadIdx.y;
#pragma unroll
    for (int i = 0; i < 32; i += 8)
        tile[ty + i][tx] = feat[((size_t)b * D_MODEL + d0 + ty + i) * NPTS + n0 + tx];
    __syncthreads();
#pragma unroll
    for (int i = 0; i < 32; i += 8)
        f[((size_t)b * NPTS + n0 + ty + i) * D_MODEL + d0 + tx] = f2bf(tile[tx][ty + i]);
}

// FFIN bf16 [B, N, D] -> out fp32 [B, D, N]
__global__ __launch_bounds__(256) void k_transpose_out(const unsigned short* __restrict__ f,
                                                       float* __restrict__ out) {
    __shared__ float tile[32][33];
    int b = blockIdx.z;
    int d0 = blockIdx.x * 32, n0 = blockIdx.y * 32;
    int tx = threadIdx.x, ty = threadIdx.y;
#pragma unroll
    for (int i = 0; i < 32; i += 8)
        tile[ty + i][tx] = bf2f(f[((size_t)b * NPTS + n0 + ty + i) * D_MODEL + d0 + tx]);
    __syncthreads();
#pragma unroll
    for (int i = 0; i < 32; i += 8)
        out[((size_t)b * D_MODEL + d0 + ty + i) * NPTS + n0 + tx] = tile[tx][ty + i];
}

// V slice of QKV [M,1152] (cols 768..1152) -> VT [B,H,64,NPTS]
__global__ __launch_bounds__(256) void k_vt(const unsigned short* __restrict__ qkv,
                                            unsigned short* __restrict__ vt) {
    __shared__ unsigned short tile[32][33];
    int b = blockIdx.z;
    int h = blockIdx.y >> 1, d0 = (blockIdx.y & 1) * 32;
    int n0 = blockIdx.x * 32;
    int tx = threadIdx.x, ty = threadIdx.y;
#pragma unroll
    for (int i = 0; i < 32; i += 8)
        tile[ty + i][tx] =
            qkv[((size_t)b * NPTS + n0 + ty + i) * 1152 + 768 + h * 64 + d0 + tx];
    __syncthreads();
#pragma unroll
    for (int i = 0; i < 32; i += 8)
        vt[(((size_t)(b * NHEAD + h) * 64) + d0 + ty + i) * NPTS + n0 + tx] = tile[tx][ty + i];
}

// LayerNorm over D=384 (bf16 in/out, fp32 g/b), one block (128 thr) per row
__global__ __launch_bounds__(128) void k_layernorm(const unsigned short* __restrict__ x,
                                                   const float* __restrict__ g,
                                                   const float* __restrict__ bt,
                                                   unsigned short* __restrict__ y) {
    int row = blockIdx.x, t = threadIdx.x;
    const unsigned short* xr = x + (size_t)row * D_MODEL;
    float v0 = bf2f(xr[t]), v1 = bf2f(xr[t + 128]), v2 = bf2f(xr[t + 256]);
    float s = v0 + v1 + v2;
    float s2 = v0 * v0 + v1 * v1 + v2 * v2;
#pragma unroll
    for (int off = 32; off > 0; off >>= 1) {
        s += __shfl_xor(s, off, 64);
        s2 += __shfl_xor(s2, off, 64);
    }
    __shared__ float ps[2], ps2[2];
    if ((t & 63) == 0) { ps[t >> 6] = s; ps2[t >> 6] = s2; }
    __syncthreads();
    s = ps[0] + ps[1];
    s2 = ps2[0] + ps2[1];
    float mean = s * (1.0f / 384.0f);
    float var = s2 * (1.0f / 384.0f) - mean * mean;
    var = fmaxf(var, 0.0f);
    float inv = 1.0f / sqrtf(var + 1e-5f);
    unsigned short* yr = y + (size_t)row * D_MODEL;
    yr[t]       = f2bf((v0 - mean) * inv * g[t]       + bt[t]);
    yr[t + 128] = f2bf((v1 - mean) * inv * g[t + 128] + bt[t + 128]);
    yr[t + 256] = f2bf((v2 - mean) * inv * g[t + 256] + bt[t + 256]);
}

// KNN: LDS-resident candidates, 8 threads/query, interleaved partitions.
__global__ __launch_bounds__(256) void k_knn(const float* __restrict__ coords,
                                             int* __restrict__ idx) {
    __shared__ float4 cpts[NPTS];
    __shared__ unsigned long long mbuf[32][8][8];
    int b = blockIdx.x >> 6;
    int n0 = (blockIdx.x & 63) * 32;
    const float* cb = coords + (size_t)b * 3 * NPTS;
    int tid = threadIdx.x;
#pragma unroll
    for (int i = 0; i < 8; i++) {
        int m = tid + i * 256;
        float x = cb[m], y = cb[NPTS + m], z = cb[2 * NPTS + m];
        float sq = __fadd_rn(__fadd_rn(__fmul_rn(x, x), __fmul_rn(y, y)), __fmul_rn(z, z));
        cpts[m] = make_float4(x, y, z, sq);
    }
    __syncthreads();
    int q = tid >> 3;
    int part = tid & 7;
    int n = n0 + q;
    float4 qp = cpts[n];
    float qx = qp.x, qy = qp.y, qz = qp.z, sqn = qp.w;
    unsigned long long heap[8];
#pragma unroll
    for (int k = 0; k < 8; k++) heap[k] = 0xFFFFFFFFFFFFFFFFull;
    for (int j = 0; j < 256; j++) {
        int m = j * 8 + part;
        float4 cp = cpts[m];
        float dot = __fadd_rn(__fadd_rn(__fmul_rn(qx, cp.x), __fmul_rn(qy, cp.y)),
                              __fmul_rn(qz, cp.z));
        float d2 = __fsub_rn(__fadd_rn(sqn, cp.w), __fmul_rn(2.0f, dot));
        unsigned int u = __float_as_uint(d2);
        u = (u & 0x80000000u) ? ~u : (u | 0x80000000u);
        unsigned long long key = ((unsigned long long)u << 32) | (unsigned int)m;
        if (key < heap[7]) {
            heap[7] = key;
#pragma unroll
            for (int t2 = 7; t2 > 0; t2--) {
                if (heap[t2] < heap[t2 - 1]) {
                    unsigned long long tmp = heap[t2];
                    heap[t2] = heap[t2 - 1];
                    heap[t2 - 1] = tmp;
                }
            }
        }
    }
#pragma unroll
    for (int k = 0; k < 8; k++) mbuf[q][part][k] = heap[k];
    __syncthreads();
    if (part == 0) {
        int p[8] = {0, 0, 0, 0, 0, 0, 0, 0};
        int* outr = idx + ((size_t)b * NPTS + n) * 8;
#pragma unroll
        for (int k = 0; k < 8; k++) {
            unsigned long long best = mbuf[q][0][p[0]];
            int bi = 0;
#pragma unroll
            for (int c = 1; c < 8; c++) {
                unsigned long long v = mbuf[q][c][p[c]];
                if (v < best) { best = v; bi = c; }
            }
            p[bi]++;
            outr[k] = (int)(best & 0xFFFFFFFFu);
        }
    }
}

// MFMA GEMM v5: 128x128 tile, BK=64. BOTH operands staged to LDS via async
// global_load_lds (16B, zero staging VALU), layout = two 128x32 chunks per
// operand (pitch 64B, proven v3 bank pattern). Operand-swapped MFMA
// (acc = W_frag x A_frag = C^T layout) so the epilogue's 4 acc regs per lane
// are contiguous columns -> ushort4 stores, uint2 res loads, float4 bias.
// A bf16 [M,K] (lda), WT bf16 [N,K], bias fp32, res/C bf16 (ldc).
__global__ __launch_bounds__(256) void k_gemm(const unsigned short* __restrict__ A, int lda,
                                              const unsigned short* __restrict__ WT,
                                              const float* __restrict__ bias,
                                              const unsigned short* __restrict__ res,
                                              unsigned short* __restrict__ C, int ldc,
                                              int K, int act) {
    __shared__ unsigned short Alds[2 * 128 * 32];  // 16 KB: [kc][row][32]
    __shared__ unsigned short Wlds[2 * 128 * 32];  // 16 KB: [kc][nrow][32]
    int tid = threadIdx.x;
    int wv = tid >> 6, lane = tid & 63;
    int l15 = lane & 15, quad = lane >> 4;
    int row0 = blockIdx.y * 128, col0 = blockIdx.x * 128;
    int wm = wv >> 1, wn = wv & 1;
    int wbase = tid & 192;  // wv*64
    floatx4 acc[4][4];
#pragma unroll
    for (int i = 0; i < 4; i++)
#pragma unroll
        for (int j = 0; j < 4; j++) acc[i][j] = (floatx4){0.f, 0.f, 0.f, 0.f};
    for (int k0 = 0; k0 < K; k0 += 64) {
#pragma unroll
        for (int i = 0; i < 4; i++) {
            int idx = i * 256 + tid;
            int kc = idx >> 9, row = (idx >> 2) & 127, ko = idx & 3;
            unsigned short* ldst = Alds + (size_t)(i * 256 + wbase) * 8;  // idx*16B, wave-uniform
            gload_lds16(A + (size_t)(row0 + row) * lda + k0 + kc * 32 + ko * 8, ldst);
            unsigned short* ldstw = Wlds + (size_t)(i * 256 + wbase) * 8;
            gload_lds16(WT + (size_t)(col0 + row) * K + k0 + kc * 32 + ko * 8, ldstw);
        }
        __syncthreads();  // drains global_load_lds
#pragma unroll
        for (int kc = 0; kc < 2; kc++) {
            short8 af[4], bf[4];
#pragma unroll
            for (int i = 0; i < 4; i++)
                af[i] = *(const short8*)&Alds[kc * 4096 + (wm * 64 + i * 16 + l15) * 32 + quad * 8];
#pragma unroll
            for (int j = 0; j < 4; j++)
                bf[j] = *(const short8*)&Wlds[kc * 4096 + (wn * 64 + j * 16 + l15) * 32 + quad * 8];
#pragma unroll
            for (int i = 0; i < 4; i++)
#pragma unroll
                for (int j = 0; j < 4; j++)
                    acc[i][j] =
                        __builtin_amdgcn_mfma_f32_16x16x32_bf16(bf[j], af[i], acc[i][j], 0, 0, 0);
        }
        __syncthreads();
    }
    // acc[i][j] is C^T-layout: D rows = n (quad*4+reg within j-tile), cols = m (l15)
#pragma unroll
    for (int i = 0; i < 4; i++) {
        int r = row0 + wm * 64 + i * 16 + l15;
#pragma unroll
        for (int j = 0; j < 4; j++) {
            int cb = col0 + wn * 64 + j * 16 + quad * 4;
            float4 bv = bias ? *(const float4*)(bias + cb) : make_float4(0.f, 0.f, 0.f, 0.f);
            float v0 = acc[i][j][0] + bv.x;
            float v1 = acc[i][j][1] + bv.y;
            float v2 = acc[i][j][2] + bv.z;
            float v3 = acc[i][j][3] + bv.w;
            if (act == 1) {
                v0 = gelu_tanh(v0); v1 = gelu_tanh(v1);
                v2 = gelu_tanh(v2); v3 = gelu_tanh(v3);
            }
            if (res) {
                uint2 rv = *(const uint2*)(res + (size_t)r * ldc + cb);
                const unsigned short* rs = (const unsigned short*)&rv;
                v0 += bf2f(rs[0]); v1 += bf2f(rs[1]);
                v2 += bf2f(rs[2]); v3 += bf2f(rs[3]);
            }
            ushort4 u;
            u.x = f2bf(v0); u.y = f2bf(v1); u.z = f2bf(v2); u.w = f2bf(v3);
            *(ushort4*)(C + (size_t)r * ldc + cb) = u;
        }
    }
}

// MFMA flash attention v4: no-max softmax (p = exp2(s), Q pre-scaled by
// 0.125*log2e at load), V pre-transposed in global (VT [B,H,64,NPTS]).
__global__ __launch_bounds__(256) void k_attn(const unsigned short* __restrict__ qkv,
                                              const unsigned short* __restrict__ vt,
                                              unsigned short* __restrict__ attn) {
    __shared__ unsigned short Klds[64 * 72];       // [key][dim]
    __shared__ unsigned short VT[64 * 72];         // [dim][key]
    __shared__ unsigned short Plds[4][2][16 * 40]; // per-wave [query][key] pitch 40
    __shared__ float lSm[4][32];
    int b = blockIdx.z, h = blockIdx.y;
    int tid = threadIdx.x;
    int wv = tid >> 6, lane = tid & 63;
    int l15 = lane & 15, quad = lane >> 4;
    int qbase = blockIdx.x * 128 + wv * 32;
    const unsigned short* qkvb = qkv + (size_t)b * NPTS * 1152;
    const unsigned short* vtb = vt + (size_t)(b * NHEAD + h) * 64 * NPTS;
    const float SC = 0.18033688011112042f;  // 0.125 * log2(e)
    short8 qf[2][2];
#pragma unroll
    for (int qt = 0; qt < 2; qt++) {
        const unsigned short* qptr =
            qkvb + (size_t)(qbase + qt * 16 + l15) * 1152 + h * 64 + quad * 8;
        qf[qt][0] = *(const short8*)qptr;
        qf[qt][1] = *(const short8*)(qptr + 32);
#pragma unroll
        for (int g = 0; g < 2; g++) {  // fold softmax scale into Q once
            short8 v = qf[qt][g];
#pragma unroll
            for (int e = 0; e < 8; e++)
                v[e] = (short)f2bf(bf2f((unsigned short)v[e]) * SC);
            qf[qt][g] = v;
        }
    }
    floatx4 o[2][4];
#pragma unroll
    for (int qt = 0; qt < 2; qt++)
#pragma unroll
        for (int ct = 0; ct < 4; ct++) o[qt][ct] = (floatx4){0.f, 0.f, 0.f, 0.f};
    float lacc[2][4];
#pragma unroll
    for (int qt = 0; qt < 2; qt++)
#pragma unroll
        for (int r = 0; r < 4; r++) lacc[qt][r] = 0.0f;
    for (int k0 = 0; k0 < NPTS; k0 += 64) {
#pragma unroll
        for (int i = 0; i < 2; i++) {
            int s = tid + i * 256;
            int key = s >> 3, dg = s & 7;
            *(uint4*)&Klds[key * 72 + dg * 8] =
                *(const uint4*)(qkvb + (size_t)(k0 + key) * 1152 + 384 + h * 64 + dg * 8);
            int dim = s >> 3, kc = s & 7;
            *(uint4*)&VT[dim * 72 + kc * 8] =
                *(const uint4*)(vtb + (size_t)dim * NPTS + k0 + kc * 8);
        }
        __syncthreads();
#pragma unroll
        for (int qt = 0; qt < 2; qt++) {
            floatx4 s4[4];
#pragma unroll
            for (int ct = 0; ct < 4; ct++) {
                short8 kf0 = *(const short8*)&Klds[(ct * 16 + l15) * 72 + quad * 8];
                short8 kf1 = *(const short8*)&Klds[(ct * 16 + l15) * 72 + 32 + quad * 8];
                floatx4 z = (floatx4){0.f, 0.f, 0.f, 0.f};
                z = __builtin_amdgcn_mfma_f32_16x16x32_bf16(qf[qt][0], kf0, z, 0, 0, 0);
                z = __builtin_amdgcn_mfma_f32_16x16x32_bf16(qf[qt][1], kf1, z, 0, 0, 0);
                s4[ct] = z;
            }
            unsigned short* pw = &Plds[wv][qt][0];
#pragma unroll
            for (int ct = 0; ct < 4; ct++)
#pragma unroll
                for (int r = 0; r < 4; r++) {
                    float p = exp2f(s4[ct][r]);
                    lacc[qt][r] += p;
                    pw[(quad * 4 + r) * 40 + ct * 16 + l15] = f2bf(p);
                }
        }
        short8 pf[2][2];
#pragma unroll
        for (int qt = 0; qt < 2; qt++)
#pragma unroll
            for (int g = 0; g < 2; g++)
                pf[qt][g] = *(const short8*)&Plds[wv][qt][l15 * 40 + g * 32 + quad * 8];
#pragma unroll
        for (int ct = 0; ct < 4; ct++) {
            short8 vt0 = *(const short8*)&VT[(ct * 16 + l15) * 72 + quad * 8];
            short8 vt1 = *(const short8*)&VT[(ct * 16 + l15) * 72 + 32 + quad * 8];
#pragma unroll
            for (int qt = 0; qt < 2; qt++) {
                o[qt][ct] = __builtin_amdgcn_mfma_f32_16x16x32_bf16(vt0, pf[qt][0], o[qt][ct], 0, 0, 0);
                o[qt][ct] = __builtin_amdgcn_mfma_f32_16x16x32_bf16(vt1, pf[qt][1], o[qt][ct], 0, 0, 0);
            }
        }
        __syncthreads();
    }
#pragma unroll
    for (int off = 1; off < 16; off <<= 1)
#pragma unroll
        for (int qt = 0; qt < 2; qt++)
#pragma unroll
            for (int r = 0; r < 4; r++) lacc[qt][r] += __shfl_xor(lacc[qt][r], off, 64);
    if (l15 == 0) {
#pragma unroll
        for (int qt = 0; qt < 2; qt++)
#pragma unroll
            for (int r = 0; r < 4; r++) lSm[wv][qt * 16 + quad * 4 + r] = lacc[qt][r];
    }
#pragma unroll
    for (int qt = 0; qt < 2; qt++) {
        float linv = 1.0f / lSm[wv][qt * 16 + l15];
#pragma unroll
        for (int ct = 0; ct < 4; ct++) {
            ushort4 u;
            u.x = f2bf(o[qt][ct][0] * linv);
            u.y = f2bf(o[qt][ct][1] * linv);
            u.z = f2bf(o[qt][ct][2] * linv);
            u.w = f2bf(o[qt][ct][3] * linv);
            *(ushort4*)(attn + ((size_t)b * NPTS + qbase + qt * 16 + l15) * 384 + h * 64 +
                        ct * 16 + quad * 4) = u;
        }
    }
}

// Graph attention: gq/nk/nv are column-slices of GAP [M,1152]. One wave per point.
// Writes geom into CAT[:, 384:768] (row stride 768).
__global__ __launch_bounds__(64) void k_geom(const unsigned short* __restrict__ gap,
                                             const int* __restrict__ idx,
                                             unsigned short* __restrict__ cat) {
    int r = blockIdx.x;
    int b = r >> 11;
    int t = threadIdx.x;
    int nb[8];
#pragma unroll
    for (int k = 0; k < 8; k++) nb[k] = idx[(size_t)r * 8 + k];
    const unsigned short* gqr = gap + (size_t)r * 1152;
    float qv[6];
#pragma unroll
    for (int j = 0; j < 6; j++) qv[j] = bf2f(gqr[t + 64 * j]);
    float s[8];
#pragma unroll
    for (int k = 0; k < 8; k++) {
        const unsigned short* nkr = gap + ((size_t)b * NPTS + nb[k]) * 1152 + 384;
        float acc = 0.0f;
#pragma unroll
        for (int j = 0; j < 6; j++) acc += qv[j] * bf2f(nkr[t + 64 * j]);
#pragma unroll
        for (int mm = 32; mm > 0; mm >>= 1) acc += __shfl_xor(acc, mm, 64);
        s[k] = acc * 0.05103103630798287f;  // 1/sqrt(384)
    }
    float mx = s[0];
#pragma unroll
    for (int k = 1; k < 8; k++) mx = fmaxf(mx, s[k]);
    float w[8];
    float sum = 0.0f;
#pragma unroll
    for (int k = 0; k < 8; k++) { w[k] = __expf(s[k] - mx); sum += w[k]; }
    float inv = 1.0f / sum;
    unsigned short* outr = cat + (size_t)r * 768 + 384;
#pragma unroll
    for (int j = 0; j < 6; j++) {
        int d = t + 64 * j;
        float acc = 0.0f;
#pragma unroll
        for (int k = 0; k < 8; k++)
            acc += w[k] * bf2f(gap[((size_t)b * NPTS + nb[k]) * 1152 + 768 + d]);
        outr[d] = f2bf(acc * inv);
    }
}

extern "C" void kernel_launch(void* const* d_in, const int* in_sizes, int n_in,
                              void* d_out, int out_size, void* d_ws, size_t ws_size,
                              hipStream_t stream) {
    (void)in_sizes; (void)n_in; (void)out_size; (void)ws_size;
    const float* coords     = (const float*)d_in[0];
    const float* features   = (const float*)d_in[1];
    const float* ln1_g      = (const float*)d_in[2];
    const float* ln1_b      = (const float*)d_in[3];
    const float* w_qkv      = (const float*)d_in[4];
    const float* w_attn_out = (const float*)d_in[5];
    const float* b_attn_out = (const float*)d_in[6];
    const float* ga_wq      = (const float*)d_in[7];
    const float* ga_wk      = (const float*)d_in[8];
    const float* ga_wv      = (const float*)d_in[9];
    const float* merge_w    = (const float*)d_in[10];
    const float* merge_b    = (const float*)d_in[11];
    const float* ln2_g      = (const float*)d_in[12];
    const float* ln2_b      = (const float*)d_in[13];
    const float* ff_w1      = (const float*)d_in[14];
    const float* ff_b1      = (const float*)d_in[15];
    const float* ff_w2      = (const float*)d_in[16];
    const float* ff_b2      = (const float*)d_in[17];

    // Workspace (bf16 units of SZ = 6,291,456 elems = 12 MiB). Overlay schedule:
    //   u0 F | u1 NF->HB | u2-4 QKV -> (CAT=u2-3, GAP=u4-6 after attn/AO) |
    //   u5 ATTN | u6 VT (dead before GAP gemm) | F2=u4 after geom | T1=u5-6 |
    //   FFIN=u2 | IDX + transposed weights after u7 (~4.3 MB). Peak ~100 MiB.
    unsigned short* W0 = (unsigned short*)d_ws;
    const size_t SZ = (size_t)BATCH * NPTS * D_MODEL;  // 6291456
    unsigned short* F    = W0 + 0 * SZ;
    unsigned short* NF   = W0 + 1 * SZ;
    unsigned short* QKV  = W0 + 2 * SZ;   // 3 units
    unsigned short* ATTN = W0 + 5 * SZ;
    unsigned short* VT   = W0 + 6 * SZ;   // [B,H,64,NPTS] = 1 unit
    unsigned short* CAT  = W0 + 2 * SZ;   // 2 units [M,768]
    unsigned short* GAP  = W0 + 4 * SZ;   // 3 units [M,1152]
    unsigned short* F2   = W0 + 4 * SZ;   // after GAP dead
    unsigned short* HB   = W0 + 1 * SZ;
    unsigned short* T1   = W0 + 5 * SZ;   // 2 units [M,768]
    unsigned short* FFIN = W0 + 2 * SZ;
    int*            IDX  = (int*)(W0 + 7 * SZ);
    unsigned short* WTS  = W0 + 7 * SZ + 262144;  // after IDX (512 KB)
    unsigned short* qkvT = WTS;                     // [1152,384]
    unsigned short* aoT  = qkvT + 442368;           // [384,384]
    unsigned short* gaT  = aoT + 147456;            // [1152,384]
    unsigned short* mT   = gaT + 442368;            // [384,768]
    unsigned short* f1T  = mT + 294912;             // [768,384]
    unsigned short* f2T  = f1T + 294912;            // [384,768]

    const int M = BATCH * NPTS;  // 16384

    k_wprep<<<1872, dim3(32, 8), 0, stream>>>(w_qkv, w_attn_out, ga_wq, ga_wk, ga_wv,
                                              merge_w, ff_w1, ff_w2,
                                              qkvT, aoT, gaT, mT, f1T, f2T);
    k_transpose_in<<<dim3(NPTS / 32, D_MODEL / 32, BATCH), dim3(32, 8), 0, stream>>>(features, F);
    k_layernorm<<<M, 128, 0, stream>>>(F, ln1_g, ln1_b, NF);
    k_knn<<<BATCH * (NPTS / 32), 256, 0, stream>>>(coords, IDX);
    // QKV = NF @ w_qkv
    k_gemm<<<dim3(9, M / 128), 256, 0, stream>>>(NF, 384, qkvT, nullptr, nullptr,
                                                 QKV, 1152, 384, 0);
    k_vt<<<dim3(NPTS / 32, 2 * NHEAD, BATCH), dim3(32, 8), 0, stream>>>(QKV, VT);
    k_attn<<<dim3(NPTS / 128, NHEAD, BATCH), 256, 0, stream>>>(QKV, VT, ATTN);
    // CAT[:, :384] = ATTN @ w_attn_out + b_attn_out
    k_gemm<<<dim3(3, M / 128), 256, 0, stream>>>(ATTN, 384, aoT, b_attn_out, nullptr,
                                                 CAT, 768, 384, 0);
    // GAP = NF @ [ga_wq | ga_wk | ga_wv]
    k_gemm<<<dim3(9, M / 128), 256, 0, stream>>>(NF, 384, gaT, nullptr, nullptr,
                                                 GAP, 1152, 384, 0);
    k_geom<<<M, 64, 0, stream>>>(GAP, IDX, CAT);
    // F2 = CAT @ merge_w + merge_b + F
    k_gemm<<<dim3(3, M / 128), 256, 0, stream>>>(CAT, 768, mT, merge_b, F,
                                                 F2, 384, 768, 0);
    k_layernorm<<<M, 128, 0, stream>>>(F2, ln2_g, ln2_b, HB);
    // T1 = gelu(HB @ ff_w1 + ff_b1)
    k_gemm<<<dim3(6, M / 128), 256, 0, stream>>>(HB, 384, f1T, ff_b1, nullptr,
                                                 T1, 768, 384, 1);
    // FFIN = F2 + T1 @ ff_w2 + ff_b2
    k_gemm<<<dim3(3, M / 128), 256, 0, stream>>>(T1, 768, f2T, ff_b2, F2,
                                                 FFIN, 384, 768, 0);
    k_transpose_out<<<dim3(D_MODEL / 32, NPTS / 32, BATCH), dim3(32, 8), 0, stream>>>(
        FFIN, (float*)d_out);
}